// Round 8
// baseline (124.280 us; speedup 1.0000x reference)
//
#include <hip/hip_runtime.h>

// Problem constants: N=8, C=1024, D=128, K=64, R=256
#define N_ 8
#define C_ 1024
#define D_ 128
#define K_ 64
#define R_ 256

typedef float fvec4 __attribute__((ext_vector_type(4)));

// out[n,c,k,d] = (xhat[n,c,d] - cent[n,k,d]) / (8 * ||xhat[n,c]-cent[n,k]||)
// (softmax cancels under the per-k l2norm; final l2norm over K*D == sqrt(K)=8)
//
// R7: compute-all-then-burst. Thread t owns k=t>>2, d-quarter q=t&3.
// All 8 output float4s are finalized in registers BEFORE any store; the 8
// stores then issue back-to-back to ONE base address with immediate offsets
// (128B contiguous per thread, 8KB per wave) — no loads, shuffles, or address
// arithmetic interleaved in the store stream. Norm/dist reductions are 4-lane
// (two shfl_xor each) instead of 32-lane butterflies.
__global__ __launch_bounds__(256) void vlad_burst_kernel(
    const float* __restrict__ x,            // (N, C, D)
    const float* __restrict__ cluster,      // (N, R, D)
    const int*   __restrict__ cluster_idx,  // (K,)
    float*       __restrict__ out)          // (N, C, K*D)
{
    const int bid = blockIdx.x;
    const int n   = bid & 7;                // XCD-ish pin (neutral, keeps cent L2-local)
    const int c   = bid >> 3;
    const int nc  = (n << 10) + c;
    const int t   = threadIdx.x;
    const int q   = t & 3;                  // d-quarter: floats [32q, 32q+32)
    const int k   = t >> 2;                 // one k per thread

    // ---- loads: 8 x-float4 + 8 cent-float4 for this (k, quarter) ----
    const float* xs = x + (size_t)nc * D_ + q * 32;
    const int   cid = cluster_idx[k];
    const float* cs = cluster + ((size_t)n * R_ + cid) * D_ + q * 32;

    fvec4 xr[8], ov[8];
    #pragma unroll
    for (int j = 0; j < 8; ++j) xr[j] = *(const fvec4*)(xs + 4 * j);
    #pragma unroll
    for (int j = 0; j < 8; ++j) ov[j] = *(const fvec4*)(cs + 4 * j);

    // ---- x norm: local 32-float sum + 2 shuffles (lanes 4k..4k+3 = full row) ----
    float nx = 0.f;
    #pragma unroll
    for (int j = 0; j < 8; ++j)
        nx = fmaf(xr[j].x, xr[j].x, fmaf(xr[j].y, xr[j].y,
             fmaf(xr[j].z, xr[j].z, fmaf(xr[j].w, xr[j].w, nx))));
    nx += __shfl_xor(nx, 1);
    nx += __shfl_xor(nx, 2);
    const float rinv = 1.0f / fmaxf(sqrtf(nx), 1e-12f);
    #pragma unroll
    for (int j = 0; j < 8; ++j) xr[j] *= rinv;

    // ---- diff + distance (same 4-lane reduction) ----
    float ds = 0.f;
    #pragma unroll
    for (int j = 0; j < 8; ++j) {
        ov[j] = xr[j] - ov[j];
        ds = fmaf(ov[j].x, ov[j].x, fmaf(ov[j].y, ov[j].y,
             fmaf(ov[j].z, ov[j].z, fmaf(ov[j].w, ov[j].w, ds))));
    }
    ds += __shfl_xor(ds, 1);
    ds += __shfl_xor(ds, 2);
    const float idv = 0.125f / fmaxf(sqrtf(ds), 1e-12f);   // includes 1/sqrt(K)
    #pragma unroll
    for (int j = 0; j < 8; ++j) ov[j] *= idv;

    // ---- unbroken store burst: 8 dwordx4, one base, imm offsets 0..112B ----
    float* ob = out + (size_t)nc * (K_ * D_) + t * 32;
    #pragma unroll
    for (int j = 0; j < 8; ++j)
        *(fvec4*)(ob + 4 * j) = ov[j];
}

extern "C" void kernel_launch(void* const* d_in, const int* in_sizes, int n_in,
                              void* d_out, int out_size, void* d_ws, size_t ws_size,
                              hipStream_t stream) {
    const float* x           = (const float*)d_in[0];
    const float* cluster     = (const float*)d_in[1];
    // d_in[2] = conv_w, d_in[3] = conv_b: mathematically cancelled, unused.
    const int*   cluster_idx = (const int*)d_in[4];
    float* out = (float*)d_out;

    dim3 grid(N_ * C_), block(256);
    vlad_burst_kernel<<<grid, block, 0, stream>>>(x, cluster, cluster_idx, out);
}

// Round 9
// 51.755 us; speedup vs baseline: 2.4013x; 2.4013x over previous
//
#include <hip/hip_runtime.h>

// Problem constants: N=8, C=1024, D=128, K=64, R=256
#define N_ 8
#define C_ 1024
#define D_ 128
#define K_ 64
#define R_ 256
#define ROWS 4   // c-rows per block

typedef float fvec4 __attribute__((ext_vector_type(4)));

// out[n,c,k,d] = (xhat[n,c,d] - cent[n,k,d]) / (8 * ||xhat[n,c]-cent[n,k]||)
// (softmax cancels under the per-k l2norm; final l2norm over K*D == sqrt(K)=8)
//
// R8: multi-row blocks. Same per-row pipeline as the 57.0us best (half-wave
// butterfly, diff[8]/id[8] then 8-store coalesced burst), but each block owns
// 4 consecutive c-rows of one n: cent float4s load ONCE into registers and
// are reused 4x; next row's x-row load is issued before the current row's
// distance loop (prefetch). 4x fewer block heads, 4x longer store stream.
__global__ __launch_bounds__(256) void vlad_deep_kernel(
    const float* __restrict__ x,            // (N, C, D)
    const float* __restrict__ cluster,      // (N, R, D)
    const int*   __restrict__ cluster_idx,  // (K,)
    float*       __restrict__ out)          // (N, C, K*D)
{
    const int bid = blockIdx.x;
    const int n   = bid & 7;
    const int c0  = (bid >> 3) * ROWS;
    const int t   = threadIdx.x;
    const int l   = t & 31;          // lane within half-wave
    const int h   = t >> 5;          // half-wave id 0..7

    // ---- cent rows for this thread's 8 k's: loaded once, live in registers ----
    const float* cbase = cluster + (size_t)n * (R_ * D_);
    fvec4 cv[8];
    #pragma unroll
    for (int p = 0; p < 8; ++p)
        cv[p] = *(const fvec4*)(cbase + (size_t)cluster_idx[p * 8 + h] * D_ + l * 4);

    const float* xrow0 = x + (size_t)(n * C_ + c0) * D_ + l * 4;
    fvec4 xv = *(const fvec4*)xrow0;                     // row 0

    float* ob = out + (size_t)(n * C_ + c0) * (K_ * D_) + (size_t)t * 4;

    #pragma unroll
    for (int rr = 0; rr < ROWS; ++rr) {
        // prefetch next row's x before this row's compute
        fvec4 xnext;
        if (rr + 1 < ROWS)
            xnext = *(const fvec4*)(xrow0 + (size_t)(rr + 1) * D_);

        // normalize
        float nx = fmaf(xv.x, xv.x, fmaf(xv.y, xv.y, fmaf(xv.z, xv.z, xv.w * xv.w)));
        #pragma unroll
        for (int m = 1; m <= 16; m <<= 1) nx += __shfl_xor(nx, m, 32);
        const float rinv = 1.0f / fmaxf(sqrtf(nx), 1e-12f);
        xv *= rinv;

        // distances -> diff/id in registers
        fvec4 diff[8];
        float id[8];
        #pragma unroll
        for (int p = 0; p < 8; ++p) {
            fvec4 d = xv - cv[p];
            diff[p] = d;
            float ds = fmaf(d.x, d.x, fmaf(d.y, d.y, fmaf(d.z, d.z, d.w * d.w)));
            #pragma unroll
            for (int m = 1; m <= 16; m <<= 1) ds += __shfl_xor(ds, m, 32);
            id[p] = 0.125f / fmaxf(sqrtf(ds), 1e-12f);   // includes 1/sqrt(K)
        }

        // coalesced store burst (wave writes 1KB contiguous per instruction)
        float* orow = ob + (size_t)rr * (K_ * D_);
        #pragma unroll
        for (int p = 0; p < 8; ++p)
            *(fvec4*)(orow + (size_t)p * 1024) = diff[p] * id[p];

        xv = xnext;
    }
}

extern "C" void kernel_launch(void* const* d_in, const int* in_sizes, int n_in,
                              void* d_out, int out_size, void* d_ws, size_t ws_size,
                              hipStream_t stream) {
    const float* x           = (const float*)d_in[0];
    const float* cluster     = (const float*)d_in[1];
    // d_in[2] = conv_w, d_in[3] = conv_b: mathematically cancelled, unused.
    const int*   cluster_idx = (const int*)d_in[4];
    float* out = (float*)d_out;

    dim3 grid(N_ * C_ / ROWS), block(256);   // 2048 blocks
    vlad_deep_kernel<<<grid, block, 0, stream>>>(x, cluster, cluster_idx, out);
}